// Round 19
// baseline (143.224 us; speedup 1.0000x reference)
//
#include <hip/hip_runtime.h>
#include <cstdint>

#define DM    768
#define DI    1536
#define PP    64
#define HH    24
#define NN    64
#define NP1   3328   // 3224 padded to 26*128
#define LL    1024
#define ROWS  2048   // BATCH*LL
#define DINP  3224
#define EPSF  1e-5f
#define NCHUNK 16
#define CLEN   64

typedef unsigned short ushortT;
typedef __attribute__((ext_vector_type(8))) __bf16 bf16x8;
typedef __attribute__((ext_vector_type(8))) unsigned short ushort8;
typedef __attribute__((ext_vector_type(4))) unsigned short ushort4v;
typedef __attribute__((ext_vector_type(4))) float f32x4;

__device__ __forceinline__ int seqmap(int t) { return 1023 - 32 * (t & 31) - (t >> 5); }

__device__ __forceinline__ ushortT f2bf(float f) {
  union { float f; unsigned u; } v; v.f = f;
  unsigned r = v.u + 0x7FFF + ((v.u >> 16) & 1);
  return (ushortT)(r >> 16);
}
__device__ __forceinline__ float bf2f(ushortT b) {
  union { unsigned u; float f; } v; v.u = ((unsigned)b) << 16;
  return v.f;
}

__device__ __forceinline__ void gload_lds16(const void* g, void* l) {
  __builtin_amdgcn_global_load_lds((const __attribute__((address_space(1))) void*)g,
                                   (__attribute__((address_space(3))) void*)l, 16, 0, 0);
}

// swizzled ushort index into a 64x64 bf16 tile (row stride 64)
#define SWZ(r, c) ((r) * 64 + ((c) ^ (((r) & 7) << 3)))
// swizzled ushort index into a [R][64] bf16 tile (row stride 64)
#define SWZ64(r, c) ((r) * 64 + ((c) ^ (((r) & 7) << 3)))

// ---------------- prep: LN both dirs per x-row (blocks 0..2047); weight cvt (2048+) ----------------
__global__ __launch_bounds__(256) void prep_kernel(const float* __restrict__ x,
    const float* __restrict__ wf, const float* __restrict__ bf_,
    const float* __restrict__ wb, const float* __restrict__ bb,
    ushortT* __restrict__ xln,
    const float* __restrict__ fw1, const float* __restrict__ bw1,
    const float* __restrict__ fw2, const float* __restrict__ bw2,
    ushortT* __restrict__ WP1, ushortT* __restrict__ W2) {
  __shared__ float lds[4];
  int bid = blockIdx.x;
  int tid = threadIdx.x;
  if (bid < 2048) {
    int b = bid >> 10, sr = bid & 1023;
    const float* xr = x + (size_t)bid * DM;
    float v0 = xr[tid], v1 = xr[tid + 256], v2 = xr[tid + 512];
    float s = v0 + v1 + v2;
    #pragma unroll
    for (int o = 32; o; o >>= 1) s += __shfl_xor(s, o, 64);
    if ((tid & 63) == 0) lds[tid >> 6] = s;
    __syncthreads();
    float mean = (lds[0] + lds[1] + lds[2] + lds[3]) * (1.f / 768.f);
    __syncthreads();
    float d0 = v0 - mean, d1 = v1 - mean, d2 = v2 - mean;
    float q = d0 * d0 + d1 * d1 + d2 * d2;
    #pragma unroll
    for (int o = 32; o; o >>= 1) q += __shfl_xor(q, o, 64);
    if ((tid & 63) == 0) lds[tid >> 6] = q;
    __syncthreads();
    float var = (lds[0] + lds[1] + lds[2] + lds[3]) * (1.f / 768.f);
    float rs = rsqrtf(var + EPSF);
    int t1 = seqmap(sr);
    ushortT* o0 = xln + (size_t)bid * DM;
    ushortT* o1 = xln + (size_t)(2048 + b * 1024 + t1) * DM;
    o0[tid]       = f2bf(d0 * rs * wf[tid]       + bf_[tid]);
    o0[tid + 256] = f2bf(d1 * rs * wf[tid + 256] + bf_[tid + 256]);
    o0[tid + 512] = f2bf(d2 * rs * wf[tid + 512] + bf_[tid + 512]);
    o1[tid]       = f2bf(d0 * rs * wb[tid]       + bb[tid]);
    o1[tid + 256] = f2bf(d1 * rs * wb[tid + 256] + bb[tid + 256]);
    o1[tid + 512] = f2bf(d2 * rs * wb[tid + 512] + bb[tid + 512]);
  } else {
    const long NW1 = (long)NP1 * DM, SW1 = (long)DINP * DM, NW2 = (long)DM * DI;
    const long tot8 = (2 * NW1 + 2 * NW2) >> 3;
    long nb = (long)gridDim.x - 2048;
    for (long i8 = (long)(bid - 2048) * 256 + tid; i8 < tot8; i8 += nb * 256) {
      long i = i8 << 3;
      const float* src = nullptr;
      ushortT* dst;
      if (i < NW1) {
        if (i < SW1) src = fw1 + i;
        dst = WP1 + i;
      } else if (i < 2 * NW1) {
        long j = i - NW1;
        if (j < SW1) src = bw1 + j;
        dst = WP1 + i;
      } else if (i < 2 * NW1 + NW2) {
        long j = i - 2 * NW1;
        src = fw2 + j;
        dst = W2 + j;
      } else {
        long j = i - 2 * NW1 - NW2;
        src = bw2 + j;
        dst = W2 + NW2 + j;
      }
      ushort8 o = {};
      if (src) {
        float4 a = *(const float4*)src;
        float4 b2 = *(const float4*)(src + 4);
        o[0] = f2bf(a.x);  o[1] = f2bf(a.y);  o[2] = f2bf(a.z);  o[3] = f2bf(a.w);
        o[4] = f2bf(b2.x); o[5] = f2bf(b2.y); o[6] = f2bf(b2.z); o[7] = f2bf(b2.w);
      }
      *(ushort8*)dst = o;
    }
  }
}

// ---------------- 256x256 bf16 MFMA GEMM for in_proj, 4-phase split + setprio ----------------
// bf16 to Cb for cols<3200, f32 to Cf (dt tail, ld 128). K=768.
__global__ __launch_bounds__(512) void gemm256_kernel(
    const ushortT* __restrict__ Aall, const ushortT* __restrict__ Ball,
    float* __restrict__ Cfall, ushortT* __restrict__ Cball,
    int K, int lda, int ldb, int ldc, long sA, long sB, long sCf, long sCb) {
  __shared__ ushortT sA2[2][256 * 64];
  __shared__ ushortT sB2[2][256 * 64];
  int gx = gridDim.x, gy = gridDim.y;
  int nwg = gx * gy * gridDim.z;
  int lid = blockIdx.x + gx * (blockIdx.y + gy * blockIdx.z);
  int cpx = nwg >> 3;
  int swz = (lid & 7) * cpx + (lid >> 3);
  int bx = swz % gx;
  int rest = swz / gx;
  int by = rest % gy, bz = rest / gy;
  const ushortT* A = Aall + (size_t)bz * sA;
  const ushortT* B = Ball + (size_t)bz * sB;
  int tid = threadIdx.x, lane = tid & 63, w = tid >> 6;   // w 0..7
  int wm = w >> 2, wn = w & 3;
  int m0 = by * 256, n0 = bx * 256;
  int rA8 = lane >> 3;
  int cSw = ((lane & 7) << 3) ^ (((lane >> 3) & 7) << 3);   // pre-swizzled source col
  f32x4 acc[8][4] = {};
  const int NT = K >> 6;
  int fr = lane & 15, kq = lane >> 4;

  auto STAGE = [&](int bf, int kt) {
    int kc = kt * 64 + cSw;
    #pragma unroll
    for (int c2 = 0; c2 < 4; ++c2) {
      int q = w * 4 + c2;            // 0..31 (8 rows each)
      gload_lds16(A + (size_t)(m0 + q * 8 + rA8) * lda + kc, &sA2[bf][q * 512]);
    }
    #pragma unroll
    for (int c2 = 0; c2 < 4; ++c2) {
      int q = w * 4 + c2;
      gload_lds16(B + (size_t)(n0 + q * 8 + rA8) * ldb + kc, &sB2[bf][q * 512]);
    }
  };

  STAGE(0, 0);
  int cur = 0;
  for (int kt = 0; kt < NT; ++kt) {
    if (kt + 1 < NT) {
      STAGE(cur ^ 1, kt + 1);
      asm volatile("s_waitcnt vmcnt(8)" ::: "memory");   // tile kt's 8 loads done
    } else {
      asm volatile("s_waitcnt vmcnt(0)" ::: "memory");
    }
    __builtin_amdgcn_s_barrier();
    __builtin_amdgcn_sched_barrier(0);
    // 4 phases; phase p computes acc rows {2p,2p+1} over full K=64 (16 MFMA).
    // cur buffer is stable all iteration -> inner barriers are scheduling-only.
    #pragma unroll
    for (int p = 0; p < 4; ++p) {
      #pragma unroll
      for (int ks = 0; ks < 2; ++ks) {
        int kb = ks * 32 + kq * 8;
        bf16x8 a0 = *(const bf16x8*)&sA2[cur][SWZ64(wm * 128 + (2 * p) * 16 + fr, kb)];
        bf16x8 a1 = *(const bf16x8*)&sA2[cur][SWZ64(wm * 128 + (2 * p + 1) * 16 + fr, kb)];
        bf16x8 bfr[4];
        #pragma unroll
        for (int j = 0; j < 4; ++j)
          bfr[j] = *(const bf16x8*)&sB2[cur][SWZ64(wn * 64 + j * 16 + fr, kb)];
        __builtin_amdgcn_s_setprio(1);
        #pragma unroll
        for (int j = 0; j < 4; ++j) {
          acc[2 * p][j]     = __builtin_amdgcn_mfma_f32_16x16x32_bf16(a0, bfr[j], acc[2 * p][j], 0, 0, 0);
          acc[2 * p + 1][j] = __builtin_amdgcn_mfma_f32_16x16x32_bf16(a1, bfr[j], acc[2 * p + 1][j], 0, 0, 0);
        }
        __builtin_amdgcn_s_setprio(0);
      }
      if (p < 3) {
        __builtin_amdgcn_s_barrier();
        __builtin_amdgcn_sched_barrier(0);
      }
    }
    asm volatile("s_waitcnt lgkmcnt(0)" ::: "memory");
    __builtin_amdgcn_sched_barrier(0);
    __builtin_amdgcn_s_barrier();
    cur ^= 1;
  }
  int cr = (lane >> 4) * 4, cc = lane & 15;
  #pragma unroll
  for (int i = 0; i < 8; ++i)
    #pragma unroll
    for (int j = 0; j < 4; ++j) {
      int gr = m0 + wm * 128 + i * 16 + cr;
      int gc = n0 + wn * 64 + j * 16 + cc;
      if (gc < 3200) {
        ushortT* Cp = Cball + (size_t)bz * sCb + (size_t)gr * ldc + gc;
        #pragma unroll
        for (int r = 0; r < 4; ++r) Cp[(size_t)r * ldc] = f2bf(acc[i][j][r]);
      } else {
        float* Cp = Cfall + (size_t)bz * sCf + (size_t)gr * 128 + (gc - 3200);
        #pragma unroll
        for (int r = 0; r < 4; ++r) Cp[(size_t)r * 128] = acc[i][j][r];
      }
    }
}

// ---------------- 128x128 bf16 MFMA GEMM (out_proj): bf16 out ----------------
__global__ __launch_bounds__(256) void gemm_bf16(
    const ushortT* __restrict__ Aall, const ushortT* __restrict__ Ball,
    ushortT* __restrict__ Cball,
    int K, int lda, int ldb, int ldc, long sA, long sB, long sCb) {
  __shared__ ushortT sA2[2][128 * 64];
  __shared__ ushortT sB2[2][128 * 64];
  int gx = gridDim.x, gy = gridDim.y;
  int nwg = gx * gy * gridDim.z;
  int lid = blockIdx.x + gx * (blockIdx.y + gy * blockIdx.z);
  int cpx = nwg >> 3;
  int swz = (lid & 7) * cpx + (lid >> 3);
  int bx = swz % gx;
  int rest = swz / gx;
  int by = rest % gy, bz = rest / gy;
  const ushortT* A = Aall + (size_t)bz * sA;
  const ushortT* B = Ball + (size_t)bz * sB;
  int tid = threadIdx.x, lane = tid & 63, w = tid >> 6;
  int wm = w >> 1, wn = w & 1;
  int m0 = by * 128, n0 = bx * 128;
  int rA8 = lane >> 3;
  int cSw = ((lane & 7) << 3) ^ (((lane >> 3) & 7) << 3);
  f32x4 acc[4][4] = {};
  const int NT = K >> 6;
  int fr = lane & 15, kq = lane >> 4;

  auto STAGE = [&](int bf, int kt) {
    int kc = kt * 64 + cSw;
    #pragma unroll
    for (int c2 = 0; c2 < 4; ++c2) {
      int q = w * 4 + c2;
      gload_lds16(A + (size_t)(m0 + q * 8 + rA8) * lda + kc, &sA2[bf][q * 512]);
    }
    #pragma unroll
    for (int c2 = 0; c2 < 4; ++c2) {
      int q = w * 4 + c2;
      gload_lds16(B + (size_t)(n0 + q * 8 + rA8) * ldb + kc, &sB2[bf][q * 512]);
    }
  };

  STAGE(0, 0);
  int cur = 0;
  for (int kt = 0; kt < NT; ++kt) {
    if (kt + 1 < NT) {
      STAGE(cur ^ 1, kt + 1);
      asm volatile("s_waitcnt vmcnt(8)" ::: "memory");
    } else {
      asm volatile("s_waitcnt vmcnt(0)" ::: "memory");
    }
    __builtin_amdgcn_s_barrier();
    __builtin_amdgcn_sched_barrier(0);
    #pragma unroll
    for (int ks = 0; ks < 2; ++ks) {
      int kb = ks * 32 + kq * 8;
      bf16x8 af[4], bfr[4];
      #pragma unroll
      for (int i = 0; i < 4; ++i)
        af[i] = *(const bf16x8*)&sA2[cur][SWZ64(wm * 64 + i * 16 + fr, kb)];
      #pragma unroll
      for (int j = 0; j < 4; ++j)
        bfr[j] = *(const bf16x8*)&sB2[cur][SWZ64(wn * 64 + j * 16 + fr, kb)];
      #pragma unroll
      for (int i = 0; i < 4; ++i)
        #pragma unroll
        for (int j = 0; j < 4; ++j)
          acc[i][j] = __builtin_amdgcn_mfma_f32_16x16x32_bf16(af[i], bfr[j], acc[i][j], 0, 0, 0);
    }
    asm volatile("s_waitcnt lgkmcnt(0)" ::: "memory");
    __builtin_amdgcn_sched_barrier(0);
    __builtin_amdgcn_s_barrier();
    cur ^= 1;
  }
  int cr = (lane >> 4) * 4, cc = lane & 15;
  ushortT* Cb = Cball + (size_t)bz * sCb;
  #pragma unroll
  for (int i = 0; i < 4; ++i)
    #pragma unroll
    for (int j = 0; j < 4; ++j) {
      ushortT* Cp = Cb + (size_t)(m0 + wm * 64 + i * 16 + cr) * ldc + (n0 + wn * 64 + j * 16 + cc);
      #pragma unroll
      for (int r = 0; r < 4; ++r) Cp[(size_t)r * ldc] = f2bf(acc[i][j][r]);
    }
}

// ---------------- convbc: conv+silu for B/C, once per (dirb, chunk), pre-swizzled out ----------------
__global__ __launch_bounds__(256) void convbc_kernel(const ushortT* __restrict__ zxb,
    const float* __restrict__ cwf, const float* __restrict__ cbf,
    const float* __restrict__ cwb, const float* __restrict__ cbb,
    ushortT* __restrict__ bcc) {
  __shared__ ushortT sZ[67 * 128];
  int chunk = blockIdx.x, dirb = blockIdx.y;
  int dir = dirb >> 1;
  int t0 = chunk * 64;
  size_t rowb = (size_t)dirb * 1024;
  const float* cw = dir ? cwb : cwf;
  const float* cb = dir ? cbb : cbf;
  int tid = threadIdx.x;
  for (int idx = tid; idx < 67 * 16; idx += 256) {
    int r = idx >> 4, g = idx & 15;
    int t = t0 - 3 + r;
    ushort8 v = {};
    if (t >= 0) v = *(const ushort8*)&zxb[(rowb + t) * NP1 + 3072 + g * 8];
    *(ushort8*)&sZ[r * 128 + g * 8] = v;
  }
  __syncthreads();
  ushortT* outB = bcc + ((size_t)(dirb * NCHUNK + chunk) * 2) * 4096;
  ushortT* outC = outB + 4096;
  for (int idx = tid; idx < 64 * 16; idx += 256) {
    int r = idx >> 4, g = idx & 15;
    int cc8 = g * 8;
    ushort8 x0 = *(const ushort8*)&sZ[(r + 0) * 128 + cc8];
    ushort8 x1 = *(const ushort8*)&sZ[(r + 1) * 128 + cc8];
    ushort8 x2 = *(const ushort8*)&sZ[(r + 2) * 128 + cc8];
    ushort8 x3 = *(const ushort8*)&sZ[(r + 3) * 128 + cc8];
    ushort8 o;
    #pragma unroll
    for (int e = 0; e < 8; ++e) {
      int gc = 1536 + cc8 + e;   // conv-domain channel
      float a = cb[gc] + bf2f(x0[e]) * cw[gc * 4 + 0] + bf2f(x1[e]) * cw[gc * 4 + 1]
              + bf2f(x2[e]) * cw[gc * 4 + 2] + bf2f(x3[e]) * cw[gc * 4 + 3];
      o[e] = f2bf(a / (1.f + __expf(-a)));
    }
    if (cc8 < 64) *(ushort8*)&outB[SWZ(r, cc8)] = o;
    else          *(ushort8*)&outC[SWZ(r, cc8 - 64)] = o;
  }
}

// ---------------- pass 1: fused X-conv + SSD chunk + D*x, block per (gh, chunk) ----------------
__global__ __launch_bounds__(256) void ssd_chunk_kernel(const ushortT* __restrict__ zxb,
    const ushortT* __restrict__ bcc,
    const float* __restrict__ dtt,
    const float* __restrict__ cwf, const float* __restrict__ cbf,
    const float* __restrict__ cwb, const float* __restrict__ cbb,
    const float* __restrict__ dtbf, const float* __restrict__ alogf,
    const float* __restrict__ dtbb, const float* __restrict__ alogb,
    const float* __restrict__ Df, const float* __restrict__ Db,
    ushortT* __restrict__ yb, ushortT* __restrict__ slocb, float* __restrict__ cwg) {
  __shared__ ushortT sCb[4096];   // [t][n] conv'd C (gloaded, swizzled)
  __shared__ ushortT sBb[4096];   // [s][n] conv'd B (gloaded, swizzled)
  __shared__ ushortT sXT[4096];   // [p][t] conv'd X transposed
  __shared__ ushortT sPool[8192]; // phase0: sRawX (stride 72); phase2+: sBT | sMb
  __shared__ float clog[64];
  __shared__ float dt64[64];
  __shared__ float wv64[64];
  ushortT* sBT   = sPool;          // [n][t] weighted B^T   (phase 2+)
  ushortT* sMb   = sPool + 4096;   // [t][s] decay matrix   (phase 2+)
  ushortT* sRawX = sPool;          // [67][72] raw X        (phase 0-0b only)

  int gh = blockIdx.x;                 // dir*48 + b*24 + h
  int c  = blockIdx.y;                 // chunk
  int dir = gh / 48;
  int rem = gh % 48;
  int b = rem / 24, h = rem % 24;
  int tid = threadIdx.x, lane = tid & 63;
  int w = tid >> 6;
  int dirb = dir * 2 + b;
  size_t rowbase = (size_t)dirb * 1024;
  int t0 = c * CLEN;
  size_t trow = rowbase + (size_t)t0;
  const float* cw   = dir ? cwb : cwf;
  const float* cb   = dir ? cbb : cbf;
  const float* dtb  = dir ? dtbb : dtbf;
  const float* alog = dir ? alogb : alogf;
  float Dv = (dir ? Db : Df)[h];

  // ---- phase 0: gload B/C tiles; stage raw X (stride 72); dt scan ----
  {
    const ushortT* bSrc = bcc + ((size_t)(dirb * NCHUNK + c) * 2) * 4096;
    const ushortT* cSrc = bSrc + 4096;
    #pragma unroll
    for (int ph = 0; ph < 2; ++ph) {
      int base = ph * 2048 + w * 512;
      gload_lds16(bSrc + base + lane * 8, &sBb[base]);
      gload_lds16(cSrc + base + lane * 8, &sCb[base]);
    }
  }
  for (int idx = tid; idx < 67 * 8; idx += 256) {    // X: raw cols 1536 + h*64 ..
    int r = idx >> 3, g = idx & 7;
    int t = t0 - 3 + r;
    ushort8 v = {};
    if (t >= 0) v = *(const ushort8*)&zxb[(rowbase + t) * NP1 + 1536 + h * 64 + g * 8];
    *(ushort8*)&sRawX[r * 72 + g * 8] = v;
  }
  if (tid < 64) {
    float raw = dtt[(trow + tid) * 128 + h] + dtb[h];
    float dtv = raw > 20.f ? raw : log1pf(expf(raw));
    float ld = -expf(alog[h]) * dtv;        // log dA (negative)
    float v = ld;
    #pragma unroll
    for (int o = 1; o < 64; o <<= 1) {
      float u = __shfl_up(v, o, 64);
      if (tid >= o) v += u;
    }
    float tot = __shfl(v, 63, 64);
    clog[tid] = v;
    dt64[tid] = dtv;
    wv64[tid] = dtv * __expf(tot - v);
    cwg[(trow + tid) * HH + h] = __expf(v);
  }
  __syncthreads();   // drains gload vmcnt too

  // ---- phase 0b: X conv+silu -> sXT (transposed) ----
  {
    int p = lane;
    int ch = h * 64 + p;        // conv-domain channel (X block of CONVD)
    float cbv = cb[ch];
    float w0 = cw[ch * 4], w1 = cw[ch * 4 + 1], w2 = cw[ch * 4 + 2], w3 = cw[ch * 4 + 3];
    #pragma unroll
    for (int q = 0; q < 4; ++q) {
      int t4 = w * 16 + q * 4;
      float rv[7];
      #pragma unroll
      for (int rr = 0; rr < 7; ++rr) rv[rr] = bf2f(sRawX[(t4 + rr) * 72 + p]);
      ushort4v v4;
      #pragma unroll
      for (int i = 0; i < 4; ++i) {
        float a = cbv + rv[i] * w0 + rv[i + 1] * w1 + rv[i + 2] * w2 + rv[i + 3] * w3;
        v4[i] = f2bf(a / (1.f + __expf(-a)));
      }
      int cT = t4 ^ ((p & 7) << 3);
      *(ushort4v*)&sXT[p * 64 + cT] = v4;
    }
  }
  __syncthreads();

  int fr = lane & 15, kq = lane >> 4;

  // ---- phase 2: weighted B^T (b64 transpose); G = C.B^T; decay -> M(bf16) ----
  {
    int n = lane;
    #pragma unroll
    for (int q = 0; q < 4; ++q) {
      int s4 = w * 16 + q * 4;
      float b0 = bf2f(sBb[SWZ(s4 + 0, n)]) * wv64[s4 + 0];
      float b1 = bf2f(sBb[SWZ(s4 + 1, n)]) * wv64[s4 + 1];
      float b2 = bf2f(sBb[SWZ(s4 + 2, n)]) * wv64[s4 + 2];
      float b3 = bf2f(sBb[SWZ(s4 + 3, n)]) * wv64[s4 + 3];
      int cT = s4 ^ ((n & 7) << 3);
      ushort4v v4 = {f2bf(b0), f2bf(b1), f2bf(b2), f2bf(b3)};
      *(ushort4v*)&sBT[n * 64 + cT] = v4;
    }
  }
  f32x4 accG[4] = {};
  #pragma unroll
  for (int kt = 0; kt < 2; ++kt) {
    int kk = kt * 32 + kq * 8;
    bf16x8 af = *(const bf16x8*)&sCb[SWZ(w * 16 + fr, kk)];
    #pragma unroll
    for (int j = 0; j < 4; ++j) {
      bf16x8 bf_ = *(const bf16x8*)&sBb[SWZ(j * 16 + fr, kk)];
      accG[j] = __builtin_amdgcn_mfma_f32_16x16x32_bf16(af, bf_, accG[j], 0, 0, 0);
    }
  }
  #pragma unroll
  for (int j = 0; j < 4; ++j) {
    int s = j * 16 + fr;
    float cls = clog[s], dtv = dt64[s];
    #pragma unroll
    for (int r = 0; r < 4; ++r) {
      int t = w * 16 + kq * 4 + r;
      float dec = (s <= t) ? __expf(clog[t] - cls) * dtv : 0.f;
      sMb[SWZ(t, s)] = f2bf(accG[j][r] * dec);
    }
  }
  __syncthreads();

  // ---- phase 3: Y = M.X + D*x ; S = wB^T.X (shared X fragments) ----
  f32x4 accY[4] = {}, accS[4] = {};
  #pragma unroll
  for (int kt = 0; kt < 2; ++kt) {
    int kk = kt * 32 + kq * 8;
    bf16x8 aM = *(const bf16x8*)&sMb[SWZ(w * 16 + fr, kk)];
    bf16x8 aB = *(const bf16x8*)&sBT[SWZ(w * 16 + fr, kk)];
    #pragma unroll
    for (int j = 0; j < 4; ++j) {
      bf16x8 bx = *(const bf16x8*)&sXT[SWZ(j * 16 + fr, kk)];
      accY[j] = __builtin_amdgcn_mfma_f32_16x16x32_bf16(aM, bx, accY[j], 0, 0, 0);
      accS[j] = __builtin_amdgcn_mfma_f32_16x16x32_bf16(aB, bx, accS[j], 0, 0, 0);
    }
  }
  ushortT* spb = slocb + ((size_t)gh * NCHUNK + c) * 4096;
  #pragma unroll
  for (int j = 0; j < 4; ++j) {
    #pragma unroll
    for (int r = 0; r < 4; ++r) {
      int t = w * 16 + kq * 4 + r;        // row (t for Y, n for S)
      int p = j * 16 + fr;                // col
      float xval = bf2f(sXT[SWZ(p, t)]);
      yb[(trow + t) * DI + h * 64 + p] = f2bf(accY[j][r] + Dv * xval);
      spb[t * 64 + p] = f2bf(accS[j][r]);
    }
  }
}

// ---------------- pass 2: serial prefix over chunk states (96 blocks) ----------------
__global__ __launch_bounds__(256) void chunk_prefix_kernel(
    const ushortT* __restrict__ slocb, const float* __restrict__ cwg,
    ushortT* __restrict__ sinitb) {
  __shared__ float ldsT[64 * 65];
  int gh = blockIdx.x;
  int dir = gh / 48;
  int rem = gh % 48;
  int b = rem / 24, h = rem % 24;
  int tid = threadIdx.x;
  size_t rowbase = ((size_t)dir * 2 + b) * 1024;
  float R[16];
  #pragma unroll
  for (int j = 0; j < 16; ++j) R[j] = 0.f;
  for (int c = 1; c < NCHUNK; ++c) {
    float W = cwg[(rowbase + (size_t)c * CLEN - 1) * HH + h];
    const ushortT* slot = slocb + ((size_t)gh * NCHUNK + (c - 1)) * 4096;
    #pragma unroll
    for (int j = 0; j < 16; ++j) {
      int idx = j * 256 + tid, n = idx >> 6, p = idx & 63;
      R[j] = __builtin_fmaf(R[j], W, bf2f(slot[idx]));
      ldsT[n * 65 + p] = R[j];
    }
    __syncthreads();
    ushortT* outp = sinitb + ((size_t)gh * (NCHUNK - 1) + (c - 1)) * 4096;
    #pragma unroll
    for (int j = 0; j < 16; ++j) {
      int idx = j * 256 + tid, p = idx >> 6, n = idx & 63;
      outp[SWZ(p, n)] = f2bf(ldsT[n * 65 + p]);
    }
    __syncthreads();
  }
}

// ---------------- pass 3 (MFMA): YB[t,p] += cw[t] * (C_t . S_init), RMW ----------------
__global__ __launch_bounds__(256) void fixup_kernel(
    const ushortT* __restrict__ bcc, const ushortT* __restrict__ sinitb,
    const float* __restrict__ cwg, ushortT* __restrict__ yb) {
  __shared__ ushortT sCb[4096];
  __shared__ ushortT sST[4096];
  int gh = blockIdx.x;
  int c = blockIdx.y + 1;      // 1..15
  int dir = gh / 48;
  int rem = gh % 48;
  int b = rem / 24, h = rem % 24;
  int tid = threadIdx.x, lane = tid & 63, w = tid >> 6;
  int dirb = dir * 2 + b;
  size_t rowbase = (size_t)dirb * 1024;
  size_t trow = rowbase + (size_t)c * CLEN;
  const ushortT* cbSrc = bcc + ((size_t)(dirb * NCHUNK + c) * 2 + 1) * 4096;
  const ushortT* stSrc = sinitb + ((size_t)gh * (NCHUNK - 1) + (c - 1)) * 4096;
  #pragma unroll
  for (int ph = 0; ph < 2; ++ph) {
    int base = ph * 2048 + w * 512;
    gload_lds16(cbSrc + base + lane * 8, &sCb[base]);
    gload_lds16(stSrc + base + lane * 8, &sST[base]);
  }
  __syncthreads();
  int fr = lane & 15, kq = lane >> 4;
  f32x4 accY[4] = {};
  #pragma unroll
  for (int kt = 0; kt < 2; ++kt) {
    int kk = kt * 32 + kq * 8;
    bf16x8 aC = *(const bf16x8*)&sCb[SWZ(w * 16 + fr, kk)];
    #pragma unroll
    for (int j = 0; j < 4; ++j) {
      bf16x8 bS = *(const bf16x8*)&sST[SWZ(j * 16 + fr, kk)];
      accY[j] = __builtin_amdgcn_mfma_f32_16x16x32_bf16(aC, bS, accY[j], 0, 0, 0);
    }
  }
  float cwv[4];
  #pragma unroll
  for (int r = 0; r < 4; ++r)
    cwv[r] = cwg[(trow + w * 16 + kq * 4 + r) * HH + h];
  #pragma unroll
  for (int j = 0; j < 4; ++j)
    #pragma unroll
    for (int r = 0; r < 4; ++r) {
      int t = w * 16 + kq * 4 + r, p = j * 16 + fr;
      size_t yi = (trow + t) * DI + h * 64 + p;
      yb[yi] = f2bf(bf2f(yb[yi]) + accY[j][r] * cwv[r]);
    }
}

// ---------------- gate silu(z), RMSNorm, -> bf16 (YB already holds y+D*x) ----------------
__global__ __launch_bounds__(192) void gate_norm_kernel(
    const ushortT* __restrict__ yb,
    const ushortT* __restrict__ zxb,
    const float* __restrict__ nwf, const float* __restrict__ nwb,
    ushortT* __restrict__ yn) {
  __shared__ float lds[3];
  int bid = blockIdx.x;            // 0..4095 (dir*2048 + b*1024 + t)
  int dir = bid >> 11;
  const float* nw = dir ? nwb : nwf;
  int tid = threadIdx.x;
  int c0 = tid * 8;
  float v[8];
  float ss = 0.f;
  {
    ushort8 yv8 = *(const ushort8*)&yb[(size_t)bid * DI + c0];
    ushort8 zv8 = *(const ushort8*)&zxb[(size_t)bid * NP1 + c0];
    #pragma unroll
    for (int e = 0; e < 8; ++e) {
      float yv = bf2f(yv8[e]);
      float zv = bf2f(zv8[e]);
      yv *= zv / (1.f + expf(-zv));
      v[e] = yv;
      ss += yv * yv;
    }
  }
  #pragma unroll
  for (int o = 32; o; o >>= 1) ss += __shfl_xor(ss, o, 64);
  if ((tid & 63) == 0) lds[tid >> 6] = ss;
  __syncthreads();
  float ms = (lds[0] + lds[1] + lds[2]) * (1.f / 1536.f);
  float sc = rsqrtf(ms + EPSF);
  {
    ushort8 o8;
    #pragma unroll
    for (int e = 0; e < 8; ++e) o8[e] = f2bf(v[e] * sc * nw[c0 + e]);
    *(ushort8*)&yn[(size_t)bid * DI + c0] = o8;
  }
}

// ---------------- out[t] = 2x[t] + mf[t] + mb[SEQ[t]] (mf/mb bf16) ----------------
__global__ __launch_bounds__(128) void combine_kernel(const float* __restrict__ x,
    const ushortT* __restrict__ mf, const ushortT* __restrict__ mb,
    float* __restrict__ out) {
  int bid = blockIdx.x;   // b*1024 + t
  int b = bid >> 10, t = bid & 1023;
  int st = seqmap(t);
  int tid = threadIdx.x;
  if (tid >= 96) return;
  int c0 = tid * 8;
  ushort8 fv = *(const ushort8*)&mf[(size_t)bid * DM + c0];
  ushort8 bv = *(const ushort8*)&mb[(size_t)(b * 1024 + st) * DM + c0];
  const float4 x0 = *(const float4*)&x[(size_t)bid * DM + c0];
  const float4 x1 = *(const float4*)&x[(size_t)bid * DM + c0 + 4];
  float4 o0, o1;
  o0.x = 2.f * x0.x + bf2f(fv[0]) + bf2f(bv[0]);
  o0.y = 2.f * x0.y + bf2f(fv[1]) + bf2f(bv[1]);
  o0.z = 2.f * x0.z + bf2f(fv[2]) + bf2f(bv[2]);
  o0.w = 2.f * x0.w + bf2f(fv[3]) + bf2f(bv[3]);
  o1.x = 2.f * x1.x + bf2f(fv[4]) + bf2f(bv[4]);
  o1.y = 2.f * x1.y + bf2f(fv[5]) + bf2f(bv[5]);
  o1.z = 2.f * x1.z + bf2f(fv[6]) + bf2f(bv[6]);
  o1.w = 2.f * x1.w + bf2f(fv[7]) + bf2f(bv[7]);
  *(float4*)&out[(size_t)bid * DM + c0] = o0;
  *(float4*)&out[(size_t)bid * DM + c0 + 4] = o1;
}

extern "C" void kernel_launch(void* const* d_in, const int* in_sizes, int n_in,
                              void* d_out, int out_size, void* d_ws, size_t ws_size,
                              hipStream_t stream) {
  const float* x       = (const float*)d_in[0];
  const float* f_ln_w  = (const float*)d_in[1];
  const float* f_ln_b  = (const float*)d_in[2];
  const float* f_in_w  = (const float*)d_in[3];
  const float* f_cw    = (const float*)d_in[4];
  const float* f_cb    = (const float*)d_in[5];
  const float* f_dtb   = (const float*)d_in[6];
  const float* f_alog  = (const float*)d_in[7];
  const float* f_D     = (const float*)d_in[8];
  const float* f_nw    = (const float*)d_in[9];
  const float* f_ow    = (const float*)d_in[10];
  const float* b_ln_w  = (const float*)d_in[11];
  const float* b_ln_b  = (const float*)d_in[12];
  const float* b_in_w  = (const float*)d_in[13];
  const float* b_cw    = (const float*)d_in[14];
  const float* b_cb    = (const float*)d_in[15];
  const float* b_dtb   = (const float*)d_in[16];
  const float* b_alog  = (const float*)d_in[17];
  const float* b_D     = (const float*)d_in[18];
  const float* b_nw    = (const float*)d_in[19];
  const float* b_ow    = (const float*)d_in[20];
  float* out = (float*)d_out;

  char* ws = (char*)d_ws;
  size_t off = 0;
  auto carve = [&](size_t bytes) -> char* {
    off = (off + 255) & ~(size_t)255;
    char* p = ws + off;
    off += bytes;
    return p;
  };
  ushortT* XLN   = (ushortT*)carve((size_t)2 * ROWS * DM * 2);
  ushortT* WP1   = (ushortT*)carve((size_t)2 * NP1 * DM * 2);
  ushortT* W2    = (ushortT*)carve((size_t)2 * DM * DI * 2);
  ushortT* ZXB   = (ushortT*)carve((size_t)2 * ROWS * NP1 * 2);
  float*   DTT   = (float*)carve((size_t)2 * ROWS * 128 * 4);
  ushortT* YB    = (ushortT*)carve((size_t)2 * ROWS * DI * 2);
  ushortT* YN    = (ushortT*)carve((size_t)2 * ROWS * DI * 2);
  ushortT* MOUTB = (ushortT*)carve((size_t)2 * ROWS * DM * 2);
  ushortT* SLOCB = (ushortT*)carve((size_t)96 * NCHUNK * 4096 * 2);
  ushortT* SINIB = (ushortT*)carve((size_t)96 * (NCHUNK - 1) * 4096 * 2);
  ushortT* BCC   = (ushortT*)carve((size_t)4 * NCHUNK * 2 * 4096 * 2);
  float*   CWG   = (float*)carve((size_t)2 * ROWS * HH * 4);

  // LN both dirs per x-row (blocks 0..2047) + weight cvt (2048+)
  prep_kernel<<<4096, 256, 0, stream>>>(x, f_ln_w, f_ln_b, b_ln_w, b_ln_b, XLN,
                                        f_in_w, b_in_w, f_ow, b_ow, WP1, W2);

  // in_proj: [2048,768] x [3328,768]^T (256x256 tile, 8 waves, 4-phase + setprio)
  gemm256_kernel<<<dim3(NP1 / 256, ROWS / 256, 2), 512, 0, stream>>>(
      XLN, WP1, DTT, ZXB, DM, DM, DM, NP1,
      (long)ROWS * DM, (long)NP1 * DM, (long)ROWS * 128, (long)ROWS * NP1);

  // B/C conv once per (dirb, chunk), pre-swizzled
  convbc_kernel<<<dim3(NCHUNK, 4), 256, 0, stream>>>(ZXB, f_cw, f_cb, b_cw, b_cb, BCC);

  // fused X-conv + SSD pass 1 (+ D*x)
  ssd_chunk_kernel<<<dim3(96, NCHUNK), 256, 0, stream>>>(
      ZXB, BCC, DTT, f_cw, f_cb, b_cw, b_cb, f_dtb, f_alog, b_dtb, b_alog,
      f_D, b_D, YB, SLOCB, CWG);

  // pass 2 (prefix), pass 3 (MFMA fixup, RMW into YB)
  chunk_prefix_kernel<<<96, 256, 0, stream>>>(SLOCB, CWG, SINIB);
  fixup_kernel<<<dim3(96, NCHUNK - 1), 256, 0, stream>>>(BCC, SINIB, CWG, YB);

  // gate + rmsnorm
  gate_norm_kernel<<<4096, 192, 0, stream>>>(YB, ZXB, f_nw, b_nw, YN);

  // out_proj: [2048,1536] x [768,1536]^T -> bf16 MOUTB
  gemm_bf16<<<dim3(DM / 128, ROWS / 128, 2), 256, 0, stream>>>(
      YN, W2, MOUTB, DI, DI, DI, DM,
      (long)ROWS * DI, (long)DM * DI, (long)ROWS * DM);

  // combine
  combine_kernel<<<2048, 128, 0, stream>>>(x, MOUTB, MOUTB + (size_t)ROWS * DM, out);
}

// Round 20
// 139.770 us; speedup vs baseline: 1.0247x; 1.0247x over previous
//
#include <hip/hip_runtime.h>
#include <cstdint>

#define DM    768
#define DI    1536
#define PP    64
#define HH    24
#define NN    64
#define NP1   3328   // 3224 padded to 26*128
#define LL    1024
#define ROWS  2048   // BATCH*LL
#define DINP  3224
#define EPSF  1e-5f
#define NCHUNK 16
#define CLEN   64

typedef unsigned short ushortT;
typedef __attribute__((ext_vector_type(8))) __bf16 bf16x8;
typedef __attribute__((ext_vector_type(8))) unsigned short ushort8;
typedef __attribute__((ext_vector_type(4))) unsigned short ushort4v;
typedef __attribute__((ext_vector_type(4))) float f32x4;

__device__ __forceinline__ int seqmap(int t) { return 1023 - 32 * (t & 31) - (t >> 5); }

__device__ __forceinline__ ushortT f2bf(float f) {
  union { float f; unsigned u; } v; v.f = f;
  unsigned r = v.u + 0x7FFF + ((v.u >> 16) & 1);
  return (ushortT)(r >> 16);
}
__device__ __forceinline__ float bf2f(ushortT b) {
  union { unsigned u; float f; } v; v.u = ((unsigned)b) << 16;
  return v.f;
}

__device__ __forceinline__ void gload_lds16(const void* g, void* l) {
  __builtin_amdgcn_global_load_lds((const __attribute__((address_space(1))) void*)g,
                                   (__attribute__((address_space(3))) void*)l, 16, 0, 0);
}

// swizzled ushort index into a 64x64 bf16 tile (row stride 64)
#define SWZ(r, c) ((r) * 64 + ((c) ^ (((r) & 7) << 3)))
// swizzled ushort index into a [R][64] bf16 tile (row stride 64)
#define SWZ64(r, c) ((r) * 64 + ((c) ^ (((r) & 7) << 3)))

// ---------------- prep: LN both dirs per x-row (blocks 0..2047); weight cvt (2048+) ----------------
__global__ __launch_bounds__(256) void prep_kernel(const float* __restrict__ x,
    const float* __restrict__ wf, const float* __restrict__ bf_,
    const float* __restrict__ wb, const float* __restrict__ bb,
    ushortT* __restrict__ xln,
    const float* __restrict__ fw1, const float* __restrict__ bw1,
    const float* __restrict__ fw2, const float* __restrict__ bw2,
    ushortT* __restrict__ WP1, ushortT* __restrict__ W2) {
  __shared__ float lds[4];
  int bid = blockIdx.x;
  int tid = threadIdx.x;
  if (bid < 2048) {
    int b = bid >> 10, sr = bid & 1023;
    const float* xr = x + (size_t)bid * DM;
    float v0 = xr[tid], v1 = xr[tid + 256], v2 = xr[tid + 512];
    float s = v0 + v1 + v2;
    #pragma unroll
    for (int o = 32; o; o >>= 1) s += __shfl_xor(s, o, 64);
    if ((tid & 63) == 0) lds[tid >> 6] = s;
    __syncthreads();
    float mean = (lds[0] + lds[1] + lds[2] + lds[3]) * (1.f / 768.f);
    __syncthreads();
    float d0 = v0 - mean, d1 = v1 - mean, d2 = v2 - mean;
    float q = d0 * d0 + d1 * d1 + d2 * d2;
    #pragma unroll
    for (int o = 32; o; o >>= 1) q += __shfl_xor(q, o, 64);
    if ((tid & 63) == 0) lds[tid >> 6] = q;
    __syncthreads();
    float var = (lds[0] + lds[1] + lds[2] + lds[3]) * (1.f / 768.f);
    float rs = rsqrtf(var + EPSF);
    int t1 = seqmap(sr);
    ushortT* o0 = xln + (size_t)bid * DM;
    ushortT* o1 = xln + (size_t)(2048 + b * 1024 + t1) * DM;
    o0[tid]       = f2bf(d0 * rs * wf[tid]       + bf_[tid]);
    o0[tid + 256] = f2bf(d1 * rs * wf[tid + 256] + bf_[tid + 256]);
    o0[tid + 512] = f2bf(d2 * rs * wf[tid + 512] + bf_[tid + 512]);
    o1[tid]       = f2bf(d0 * rs * wb[tid]       + bb[tid]);
    o1[tid + 256] = f2bf(d1 * rs * wb[tid + 256] + bb[tid + 256]);
    o1[tid + 512] = f2bf(d2 * rs * wb[tid + 512] + bb[tid + 512]);
  } else {
    const long NW1 = (long)NP1 * DM, SW1 = (long)DINP * DM, NW2 = (long)DM * DI;
    const long tot8 = (2 * NW1 + 2 * NW2) >> 3;
    long nb = (long)gridDim.x - 2048;
    for (long i8 = (long)(bid - 2048) * 256 + tid; i8 < tot8; i8 += nb * 256) {
      long i = i8 << 3;
      const float* src = nullptr;
      ushortT* dst;
      if (i < NW1) {
        if (i < SW1) src = fw1 + i;
        dst = WP1 + i;
      } else if (i < 2 * NW1) {
        long j = i - NW1;
        if (j < SW1) src = bw1 + j;
        dst = WP1 + i;
      } else if (i < 2 * NW1 + NW2) {
        long j = i - 2 * NW1;
        src = fw2 + j;
        dst = W2 + j;
      } else {
        long j = i - 2 * NW1 - NW2;
        src = bw2 + j;
        dst = W2 + NW2 + j;
      }
      ushort8 o = {};
      if (src) {
        float4 a = *(const float4*)src;
        float4 b2 = *(const float4*)(src + 4);
        o[0] = f2bf(a.x);  o[1] = f2bf(a.y);  o[2] = f2bf(a.z);  o[3] = f2bf(a.w);
        o[4] = f2bf(b2.x); o[5] = f2bf(b2.y); o[6] = f2bf(b2.z); o[7] = f2bf(b2.w);
      }
      *(ushort8*)dst = o;
    }
  }
}

// ---------------- 256x256 bf16 MFMA GEMM for in_proj (2-buffer, counted vmcnt) ----------------
// bf16 to Cb for cols<3200, f32 to Cf (dt tail, ld 128). K=768.
__global__ __launch_bounds__(512) void gemm256_kernel(
    const ushortT* __restrict__ Aall, const ushortT* __restrict__ Ball,
    float* __restrict__ Cfall, ushortT* __restrict__ Cball,
    int K, int lda, int ldb, int ldc, long sA, long sB, long sCf, long sCb) {
  __shared__ ushortT sA2[2][256 * 64];
  __shared__ ushortT sB2[2][256 * 64];
  int gx = gridDim.x, gy = gridDim.y;
  int nwg = gx * gy * gridDim.z;
  int lid = blockIdx.x + gx * (blockIdx.y + gy * blockIdx.z);
  int cpx = nwg >> 3;
  int swz = (lid & 7) * cpx + (lid >> 3);
  int bx = swz % gx;
  int rest = swz / gx;
  int by = rest % gy, bz = rest / gy;
  const ushortT* A = Aall + (size_t)bz * sA;
  const ushortT* B = Ball + (size_t)bz * sB;
  int tid = threadIdx.x, lane = tid & 63, w = tid >> 6;   // w 0..7
  int wm = w >> 2, wn = w & 3;
  int m0 = by * 256, n0 = bx * 256;
  int rA8 = lane >> 3;
  int cSw = ((lane & 7) << 3) ^ (((lane >> 3) & 7) << 3);   // pre-swizzled source col
  f32x4 acc[8][4] = {};
  const int NT = K >> 6;
  int fr = lane & 15, kq = lane >> 4;

  auto STAGE = [&](int bf, int kt) {
    int kc = kt * 64 + cSw;
    #pragma unroll
    for (int c2 = 0; c2 < 4; ++c2) {
      int q = w * 4 + c2;            // 0..31 (8 rows each)
      gload_lds16(A + (size_t)(m0 + q * 8 + rA8) * lda + kc, &sA2[bf][q * 512]);
    }
    #pragma unroll
    for (int c2 = 0; c2 < 4; ++c2) {
      int q = w * 4 + c2;
      gload_lds16(B + (size_t)(n0 + q * 8 + rA8) * ldb + kc, &sB2[bf][q * 512]);
    }
  };

  STAGE(0, 0);
  int cur = 0;
  for (int kt = 0; kt < NT; ++kt) {
    if (kt + 1 < NT) {
      STAGE(cur ^ 1, kt + 1);
      asm volatile("s_waitcnt vmcnt(8)" ::: "memory");   // tile kt's 8 loads done
    } else {
      asm volatile("s_waitcnt vmcnt(0)" ::: "memory");
    }
    __builtin_amdgcn_s_barrier();
    __builtin_amdgcn_sched_barrier(0);
    #pragma unroll
    for (int ks = 0; ks < 2; ++ks) {
      int kb = ks * 32 + kq * 8;
      bf16x8 bfr[4];
      #pragma unroll
      for (int j = 0; j < 4; ++j)
        bfr[j] = *(const bf16x8*)&sB2[cur][SWZ64(wn * 64 + j * 16 + fr, kb)];
      #pragma unroll
      for (int i = 0; i < 8; ++i) {
        bf16x8 af = *(const bf16x8*)&sA2[cur][SWZ64(wm * 128 + i * 16 + fr, kb)];
        #pragma unroll
        for (int j = 0; j < 4; ++j)
          acc[i][j] = __builtin_amdgcn_mfma_f32_16x16x32_bf16(af, bfr[j], acc[i][j], 0, 0, 0);
      }
    }
    asm volatile("s_waitcnt lgkmcnt(0)" ::: "memory");
    __builtin_amdgcn_sched_barrier(0);
    __builtin_amdgcn_s_barrier();
    cur ^= 1;
  }
  int cr = (lane >> 4) * 4, cc = lane & 15;
  #pragma unroll
  for (int i = 0; i < 8; ++i)
    #pragma unroll
    for (int j = 0; j < 4; ++j) {
      int gr = m0 + wm * 128 + i * 16 + cr;
      int gc = n0 + wn * 64 + j * 16 + cc;
      if (gc < 3200) {
        ushortT* Cp = Cball + (size_t)bz * sCb + (size_t)gr * ldc + gc;
        #pragma unroll
        for (int r = 0; r < 4; ++r) Cp[(size_t)r * ldc] = f2bf(acc[i][j][r]);
      } else {
        float* Cp = Cfall + (size_t)bz * sCf + (size_t)gr * 128 + (gc - 3200);
        #pragma unroll
        for (int r = 0; r < 4; ++r) Cp[(size_t)r * 128] = acc[i][j][r];
      }
    }
}

// ---------------- 128x128 bf16 MFMA GEMM (out_proj): bf16 out ----------------
__global__ __launch_bounds__(256) void gemm_bf16(
    const ushortT* __restrict__ Aall, const ushortT* __restrict__ Ball,
    ushortT* __restrict__ Cball,
    int K, int lda, int ldb, int ldc, long sA, long sB, long sCb) {
  __shared__ ushortT sA2[2][128 * 64];
  __shared__ ushortT sB2[2][128 * 64];
  int gx = gridDim.x, gy = gridDim.y;
  int nwg = gx * gy * gridDim.z;
  int lid = blockIdx.x + gx * (blockIdx.y + gy * blockIdx.z);
  int cpx = nwg >> 3;
  int swz = (lid & 7) * cpx + (lid >> 3);
  int bx = swz % gx;
  int rest = swz / gx;
  int by = rest % gy, bz = rest / gy;
  const ushortT* A = Aall + (size_t)bz * sA;
  const ushortT* B = Ball + (size_t)bz * sB;
  int tid = threadIdx.x, lane = tid & 63, w = tid >> 6;
  int wm = w >> 1, wn = w & 1;
  int m0 = by * 128, n0 = bx * 128;
  int rA8 = lane >> 3;
  int cSw = ((lane & 7) << 3) ^ (((lane >> 3) & 7) << 3);
  f32x4 acc[4][4] = {};
  const int NT = K >> 6;
  int fr = lane & 15, kq = lane >> 4;

  auto STAGE = [&](int bf, int kt) {
    int kc = kt * 64 + cSw;
    #pragma unroll
    for (int c2 = 0; c2 < 4; ++c2) {
      int q = w * 4 + c2;
      gload_lds16(A + (size_t)(m0 + q * 8 + rA8) * lda + kc, &sA2[bf][q * 512]);
    }
    #pragma unroll
    for (int c2 = 0; c2 < 4; ++c2) {
      int q = w * 4 + c2;
      gload_lds16(B + (size_t)(n0 + q * 8 + rA8) * ldb + kc, &sB2[bf][q * 512]);
    }
  };

  STAGE(0, 0);
  int cur = 0;
  for (int kt = 0; kt < NT; ++kt) {
    if (kt + 1 < NT) {
      STAGE(cur ^ 1, kt + 1);
      asm volatile("s_waitcnt vmcnt(8)" ::: "memory");
    } else {
      asm volatile("s_waitcnt vmcnt(0)" ::: "memory");
    }
    __builtin_amdgcn_s_barrier();
    __builtin_amdgcn_sched_barrier(0);
    #pragma unroll
    for (int ks = 0; ks < 2; ++ks) {
      int kb = ks * 32 + kq * 8;
      bf16x8 af[4], bfr[4];
      #pragma unroll
      for (int i = 0; i < 4; ++i)
        af[i] = *(const bf16x8*)&sA2[cur][SWZ64(wm * 64 + i * 16 + fr, kb)];
      #pragma unroll
      for (int j = 0; j < 4; ++j)
        bfr[j] = *(const bf16x8*)&sB2[cur][SWZ64(wn * 64 + j * 16 + fr, kb)];
      #pragma unroll
      for (int i = 0; i < 4; ++i)
        #pragma unroll
        for (int j = 0; j < 4; ++j)
          acc[i][j] = __builtin_amdgcn_mfma_f32_16x16x32_bf16(af[i], bfr[j], acc[i][j], 0, 0, 0);
    }
    asm volatile("s_waitcnt lgkmcnt(0)" ::: "memory");
    __builtin_amdgcn_sched_barrier(0);
    __builtin_amdgcn_s_barrier();
    cur ^= 1;
  }
  int cr = (lane >> 4) * 4, cc = lane & 15;
  ushortT* Cb = Cball + (size_t)bz * sCb;
  #pragma unroll
  for (int i = 0; i < 4; ++i)
    #pragma unroll
    for (int j = 0; j < 4; ++j) {
      ushortT* Cp = Cb + (size_t)(m0 + wm * 64 + i * 16 + cr) * ldc + (n0 + wn * 64 + j * 16 + cc);
      #pragma unroll
      for (int r = 0; r < 4; ++r) Cp[(size_t)r * ldc] = f2bf(acc[i][j][r]);
    }
}

// ---------------- convbc: conv+silu for B/C, once per (dirb, chunk), pre-swizzled out ----------------
__global__ __launch_bounds__(256) void convbc_kernel(const ushortT* __restrict__ zxb,
    const float* __restrict__ cwf, const float* __restrict__ cbf,
    const float* __restrict__ cwb, const float* __restrict__ cbb,
    ushortT* __restrict__ bcc) {
  __shared__ ushortT sZ[67 * 128];
  int chunk = blockIdx.x, dirb = blockIdx.y;
  int dir = dirb >> 1;
  int t0 = chunk * 64;
  size_t rowb = (size_t)dirb * 1024;
  const float* cw = dir ? cwb : cwf;
  const float* cb = dir ? cbb : cbf;
  int tid = threadIdx.x;
  for (int idx = tid; idx < 67 * 16; idx += 256) {
    int r = idx >> 4, g = idx & 15;
    int t = t0 - 3 + r;
    ushort8 v = {};
    if (t >= 0) v = *(const ushort8*)&zxb[(rowb + t) * NP1 + 3072 + g * 8];
    *(ushort8*)&sZ[r * 128 + g * 8] = v;
  }
  __syncthreads();
  ushortT* outB = bcc + ((size_t)(dirb * NCHUNK + chunk) * 2) * 4096;
  ushortT* outC = outB + 4096;
  for (int idx = tid; idx < 64 * 16; idx += 256) {
    int r = idx >> 4, g = idx & 15;
    int cc8 = g * 8;
    ushort8 x0 = *(const ushort8*)&sZ[(r + 0) * 128 + cc8];
    ushort8 x1 = *(const ushort8*)&sZ[(r + 1) * 128 + cc8];
    ushort8 x2 = *(const ushort8*)&sZ[(r + 2) * 128 + cc8];
    ushort8 x3 = *(const ushort8*)&sZ[(r + 3) * 128 + cc8];
    ushort8 o;
    #pragma unroll
    for (int e = 0; e < 8; ++e) {
      int gc = 1536 + cc8 + e;   // conv-domain channel
      float a = cb[gc] + bf2f(x0[e]) * cw[gc * 4 + 0] + bf2f(x1[e]) * cw[gc * 4 + 1]
              + bf2f(x2[e]) * cw[gc * 4 + 2] + bf2f(x3[e]) * cw[gc * 4 + 3];
      o[e] = f2bf(a / (1.f + __expf(-a)));
    }
    if (cc8 < 64) *(ushort8*)&outB[SWZ(r, cc8)] = o;
    else          *(ushort8*)&outC[SWZ(r, cc8 - 64)] = o;
  }
}

// ---------------- pass 1: fused X-conv + SSD chunk + D*x, block per (gh, chunk) ----------------
__global__ __launch_bounds__(256) void ssd_chunk_kernel(const ushortT* __restrict__ zxb,
    const ushortT* __restrict__ bcc,
    const float* __restrict__ dtt,
    const float* __restrict__ cwf, const float* __restrict__ cbf,
    const float* __restrict__ cwb, const float* __restrict__ cbb,
    const float* __restrict__ dtbf, const float* __restrict__ alogf,
    const float* __restrict__ dtbb, const float* __restrict__ alogb,
    const float* __restrict__ Df, const float* __restrict__ Db,
    ushortT* __restrict__ yb, ushortT* __restrict__ slocb, float* __restrict__ cwg) {
  __shared__ ushortT sCb[4096];   // [t][n] conv'd C (gloaded, swizzled)
  __shared__ ushortT sBb[4096];   // [s][n] conv'd B (gloaded, swizzled)
  __shared__ ushortT sXT[4096];   // [p][t] conv'd X transposed
  __shared__ ushortT sPool[8192]; // phase0: sRawX (stride 72); phase2+: sBT | sMb
  __shared__ float clog[64];
  __shared__ float dt64[64];
  __shared__ float wv64[64];
  ushortT* sBT   = sPool;          // [n][t] weighted B^T   (phase 2+)
  ushortT* sMb   = sPool + 4096;   // [t][s] decay matrix   (phase 2+)
  ushortT* sRawX = sPool;          // [67][72] raw X        (phase 0-0b only)

  int gh = blockIdx.x;                 // dir*48 + b*24 + h
  int c  = blockIdx.y;                 // chunk
  int dir = gh / 48;
  int rem = gh % 48;
  int b = rem / 24, h = rem % 24;
  int tid = threadIdx.x, lane = tid & 63;
  int w = tid >> 6;
  int dirb = dir * 2 + b;
  size_t rowbase = (size_t)dirb * 1024;
  int t0 = c * CLEN;
  size_t trow = rowbase + (size_t)t0;
  const float* cw   = dir ? cwb : cwf;
  const float* cb   = dir ? cbb : cbf;
  const float* dtb  = dir ? dtbb : dtbf;
  const float* alog = dir ? alogb : alogf;
  float Dv = (dir ? Db : Df)[h];

  // ---- phase 0: gload B/C tiles; stage raw X (stride 72); dt scan ----
  {
    const ushortT* bSrc = bcc + ((size_t)(dirb * NCHUNK + c) * 2) * 4096;
    const ushortT* cSrc = bSrc + 4096;
    #pragma unroll
    for (int ph = 0; ph < 2; ++ph) {
      int base = ph * 2048 + w * 512;
      gload_lds16(bSrc + base + lane * 8, &sBb[base]);
      gload_lds16(cSrc + base + lane * 8, &sCb[base]);
    }
  }
  for (int idx = tid; idx < 67 * 8; idx += 256) {    // X: raw cols 1536 + h*64 ..
    int r = idx >> 3, g = idx & 7;
    int t = t0 - 3 + r;
    ushort8 v = {};
    if (t >= 0) v = *(const ushort8*)&zxb[(rowbase + t) * NP1 + 1536 + h * 64 + g * 8];
    *(ushort8*)&sRawX[r * 72 + g * 8] = v;
  }
  if (tid < 64) {
    float raw = dtt[(trow + tid) * 128 + h] + dtb[h];
    float dtv = raw > 20.f ? raw : log1pf(expf(raw));
    float ld = -expf(alog[h]) * dtv;        // log dA (negative)
    float v = ld;
    #pragma unroll
    for (int o = 1; o < 64; o <<= 1) {
      float u = __shfl_up(v, o, 64);
      if (tid >= o) v += u;
    }
    float tot = __shfl(v, 63, 64);
    clog[tid] = v;
    dt64[tid] = dtv;
    wv64[tid] = dtv * __expf(tot - v);
    cwg[(trow + tid) * HH + h] = __expf(v);
  }
  __syncthreads();   // drains gload vmcnt too

  // ---- phase 0b: X conv+silu -> sXT (transposed) ----
  {
    int p = lane;
    int ch = h * 64 + p;        // conv-domain channel (X block of CONVD)
    float cbv = cb[ch];
    float w0 = cw[ch * 4], w1 = cw[ch * 4 + 1], w2 = cw[ch * 4 + 2], w3 = cw[ch * 4 + 3];
    #pragma unroll
    for (int q = 0; q < 4; ++q) {
      int t4 = w * 16 + q * 4;
      float rv[7];
      #pragma unroll
      for (int rr = 0; rr < 7; ++rr) rv[rr] = bf2f(sRawX[(t4 + rr) * 72 + p]);
      ushort4v v4;
      #pragma unroll
      for (int i = 0; i < 4; ++i) {
        float a = cbv + rv[i] * w0 + rv[i + 1] * w1 + rv[i + 2] * w2 + rv[i + 3] * w3;
        v4[i] = f2bf(a / (1.f + __expf(-a)));
      }
      int cT = t4 ^ ((p & 7) << 3);
      *(ushort4v*)&sXT[p * 64 + cT] = v4;
    }
  }
  __syncthreads();

  int fr = lane & 15, kq = lane >> 4;

  // ---- phase 2: weighted B^T (b64 transpose); G = C.B^T; decay -> M(bf16) ----
  {
    int n = lane;
    #pragma unroll
    for (int q = 0; q < 4; ++q) {
      int s4 = w * 16 + q * 4;
      float b0 = bf2f(sBb[SWZ(s4 + 0, n)]) * wv64[s4 + 0];
      float b1 = bf2f(sBb[SWZ(s4 + 1, n)]) * wv64[s4 + 1];
      float b2 = bf2f(sBb[SWZ(s4 + 2, n)]) * wv64[s4 + 2];
      float b3 = bf2f(sBb[SWZ(s4 + 3, n)]) * wv64[s4 + 3];
      int cT = s4 ^ ((n & 7) << 3);
      ushort4v v4 = {f2bf(b0), f2bf(b1), f2bf(b2), f2bf(b3)};
      *(ushort4v*)&sBT[n * 64 + cT] = v4;
    }
  }
  f32x4 accG[4] = {};
  #pragma unroll
  for (int kt = 0; kt < 2; ++kt) {
    int kk = kt * 32 + kq * 8;
    bf16x8 af = *(const bf16x8*)&sCb[SWZ(w * 16 + fr, kk)];
    #pragma unroll
    for (int j = 0; j < 4; ++j) {
      bf16x8 bf_ = *(const bf16x8*)&sBb[SWZ(j * 16 + fr, kk)];
      accG[j] = __builtin_amdgcn_mfma_f32_16x16x32_bf16(af, bf_, accG[j], 0, 0, 0);
    }
  }
  #pragma unroll
  for (int j = 0; j < 4; ++j) {
    int s = j * 16 + fr;
    float cls = clog[s], dtv = dt64[s];
    #pragma unroll
    for (int r = 0; r < 4; ++r) {
      int t = w * 16 + kq * 4 + r;
      float dec = (s <= t) ? __expf(clog[t] - cls) * dtv : 0.f;
      sMb[SWZ(t, s)] = f2bf(accG[j][r] * dec);
    }
  }
  __syncthreads();

  // ---- phase 3: Y = M.X + D*x ; S = wB^T.X (shared X fragments) ----
  f32x4 accY[4] = {}, accS[4] = {};
  #pragma unroll
  for (int kt = 0; kt < 2; ++kt) {
    int kk = kt * 32 + kq * 8;
    bf16x8 aM = *(const bf16x8*)&sMb[SWZ(w * 16 + fr, kk)];
    bf16x8 aB = *(const bf16x8*)&sBT[SWZ(w * 16 + fr, kk)];
    #pragma unroll
    for (int j = 0; j < 4; ++j) {
      bf16x8 bx = *(const bf16x8*)&sXT[SWZ(j * 16 + fr, kk)];
      accY[j] = __builtin_amdgcn_mfma_f32_16x16x32_bf16(aM, bx, accY[j], 0, 0, 0);
      accS[j] = __builtin_amdgcn_mfma_f32_16x16x32_bf16(aB, bx, accS[j], 0, 0, 0);
    }
  }
  ushortT* spb = slocb + ((size_t)gh * NCHUNK + c) * 4096;
  #pragma unroll
  for (int j = 0; j < 4; ++j) {
    #pragma unroll
    for (int r = 0; r < 4; ++r) {
      int t = w * 16 + kq * 4 + r;        // row (t for Y, n for S)
      int p = j * 16 + fr;                // col
      float xval = bf2f(sXT[SWZ(p, t)]);
      yb[(trow + t) * DI + h * 64 + p] = f2bf(accY[j][r] + Dv * xval);
      spb[t * 64 + p] = f2bf(accS[j][r]);
    }
  }
}

// ---------------- pass 2: serial prefix over chunk states (96 blocks) ----------------
__global__ __launch_bounds__(256) void chunk_prefix_kernel(
    const ushortT* __restrict__ slocb, const float* __restrict__ cwg,
    ushortT* __restrict__ sinitb) {
  __shared__ float ldsT[64 * 65];
  int gh = blockIdx.x;
  int dir = gh / 48;
  int rem = gh % 48;
  int b = rem / 24, h = rem % 24;
  int tid = threadIdx.x;
  size_t rowbase = ((size_t)dir * 2 + b) * 1024;
  float R[16];
  #pragma unroll
  for (int j = 0; j < 16; ++j) R[j] = 0.f;
  for (int c = 1; c < NCHUNK; ++c) {
    float W = cwg[(rowbase + (size_t)c * CLEN - 1) * HH + h];
    const ushortT* slot = slocb + ((size_t)gh * NCHUNK + (c - 1)) * 4096;
    #pragma unroll
    for (int j = 0; j < 16; ++j) {
      int idx = j * 256 + tid, n = idx >> 6, p = idx & 63;
      R[j] = __builtin_fmaf(R[j], W, bf2f(slot[idx]));
      ldsT[n * 65 + p] = R[j];
    }
    __syncthreads();
    ushortT* outp = sinitb + ((size_t)gh * (NCHUNK - 1) + (c - 1)) * 4096;
    #pragma unroll
    for (int j = 0; j < 16; ++j) {
      int idx = j * 256 + tid, p = idx >> 6, n = idx & 63;
      outp[SWZ(p, n)] = f2bf(ldsT[n * 65 + p]);
    }
    __syncthreads();
  }
}

// ---------------- pass 3 (MFMA): YB[t,p] += cw[t] * (C_t . S_init), RMW ----------------
__global__ __launch_bounds__(256) void fixup_kernel(
    const ushortT* __restrict__ bcc, const ushortT* __restrict__ sinitb,
    const float* __restrict__ cwg, ushortT* __restrict__ yb) {
  __shared__ ushortT sCb[4096];
  __shared__ ushortT sST[4096];
  int gh = blockIdx.x;
  int c = blockIdx.y + 1;      // 1..15
  int dir = gh / 48;
  int rem = gh % 48;
  int b = rem / 24, h = rem % 24;
  int tid = threadIdx.x, lane = tid & 63, w = tid >> 6;
  int dirb = dir * 2 + b;
  size_t rowbase = (size_t)dirb * 1024;
  size_t trow = rowbase + (size_t)c * CLEN;
  const ushortT* cbSrc = bcc + ((size_t)(dirb * NCHUNK + c) * 2 + 1) * 4096;
  const ushortT* stSrc = sinitb + ((size_t)gh * (NCHUNK - 1) + (c - 1)) * 4096;
  #pragma unroll
  for (int ph = 0; ph < 2; ++ph) {
    int base = ph * 2048 + w * 512;
    gload_lds16(cbSrc + base + lane * 8, &sCb[base]);
    gload_lds16(stSrc + base + lane * 8, &sST[base]);
  }
  __syncthreads();
  int fr = lane & 15, kq = lane >> 4;
  f32x4 accY[4] = {};
  #pragma unroll
  for (int kt = 0; kt < 2; ++kt) {
    int kk = kt * 32 + kq * 8;
    bf16x8 aC = *(const bf16x8*)&sCb[SWZ(w * 16 + fr, kk)];
    #pragma unroll
    for (int j = 0; j < 4; ++j) {
      bf16x8 bS = *(const bf16x8*)&sST[SWZ(j * 16 + fr, kk)];
      accY[j] = __builtin_amdgcn_mfma_f32_16x16x32_bf16(aC, bS, accY[j], 0, 0, 0);
    }
  }
  float cwv[4];
  #pragma unroll
  for (int r = 0; r < 4; ++r)
    cwv[r] = cwg[(trow + w * 16 + kq * 4 + r) * HH + h];
  #pragma unroll
  for (int j = 0; j < 4; ++j)
    #pragma unroll
    for (int r = 0; r < 4; ++r) {
      int t = w * 16 + kq * 4 + r, p = j * 16 + fr;
      size_t yi = (trow + t) * DI + h * 64 + p;
      yb[yi] = f2bf(bf2f(yb[yi]) + accY[j][r] * cwv[r]);
    }
}

// ---------------- gate silu(z), RMSNorm, -> bf16 (YB already holds y+D*x) ----------------
__global__ __launch_bounds__(192) void gate_norm_kernel(
    const ushortT* __restrict__ yb,
    const ushortT* __restrict__ zxb,
    const float* __restrict__ nwf, const float* __restrict__ nwb,
    ushortT* __restrict__ yn) {
  __shared__ float lds[3];
  int bid = blockIdx.x;            // 0..4095 (dir*2048 + b*1024 + t)
  int dir = bid >> 11;
  const float* nw = dir ? nwb : nwf;
  int tid = threadIdx.x;
  int c0 = tid * 8;
  float v[8];
  float ss = 0.f;
  {
    ushort8 yv8 = *(const ushort8*)&yb[(size_t)bid * DI + c0];
    ushort8 zv8 = *(const ushort8*)&zxb[(size_t)bid * NP1 + c0];
    #pragma unroll
    for (int e = 0; e < 8; ++e) {
      float yv = bf2f(yv8[e]);
      float zv = bf2f(zv8[e]);
      yv *= zv / (1.f + __expf(-zv));
      v[e] = yv;
      ss += yv * yv;
    }
  }
  #pragma unroll
  for (int o = 32; o; o >>= 1) ss += __shfl_xor(ss, o, 64);
  if ((tid & 63) == 0) lds[tid >> 6] = ss;
  __syncthreads();
  float ms = (lds[0] + lds[1] + lds[2]) * (1.f / 1536.f);
  float sc = rsqrtf(ms + EPSF);
  {
    ushort8 o8;
    #pragma unroll
    for (int e = 0; e < 8; ++e) o8[e] = f2bf(v[e] * sc * nw[c0 + e]);
    *(ushort8*)&yn[(size_t)bid * DI + c0] = o8;
  }
}

// ---------------- out[t] = 2x[t] + mf[t] + mb[SEQ[t]] (mf/mb bf16) ----------------
__global__ __launch_bounds__(128) void combine_kernel(const float* __restrict__ x,
    const ushortT* __restrict__ mf, const ushortT* __restrict__ mb,
    float* __restrict__ out) {
  int bid = blockIdx.x;   // b*1024 + t
  int b = bid >> 10, t = bid & 1023;
  int st = seqmap(t);
  int tid = threadIdx.x;
  if (tid >= 96) return;
  int c0 = tid * 8;
  ushort8 fv = *(const ushort8*)&mf[(size_t)bid * DM + c0];
  ushort8 bv = *(const ushort8*)&mb[(size_t)(b * 1024 + st) * DM + c0];
  const float4 x0 = *(const float4*)&x[(size_t)bid * DM + c0];
  const float4 x1 = *(const float4*)&x[(size_t)bid * DM + c0 + 4];
  float4 o0, o1;
  o0.x = 2.f * x0.x + bf2f(fv[0]) + bf2f(bv[0]);
  o0.y = 2.f * x0.y + bf2f(fv[1]) + bf2f(bv[1]);
  o0.z = 2.f * x0.z + bf2f(fv[2]) + bf2f(bv[2]);
  o0.w = 2.f * x0.w + bf2f(fv[3]) + bf2f(bv[3]);
  o1.x = 2.f * x1.x + bf2f(fv[4]) + bf2f(bv[4]);
  o1.y = 2.f * x1.y + bf2f(fv[5]) + bf2f(bv[5]);
  o1.z = 2.f * x1.z + bf2f(fv[6]) + bf2f(bv[6]);
  o1.w = 2.f * x1.w + bf2f(fv[7]) + bf2f(bv[7]);
  *(float4*)&out[(size_t)bid * DM + c0] = o0;
  *(float4*)&out[(size_t)bid * DM + c0 + 4] = o1;
}

extern "C" void kernel_launch(void* const* d_in, const int* in_sizes, int n_in,
                              void* d_out, int out_size, void* d_ws, size_t ws_size,
                              hipStream_t stream) {
  const float* x       = (const float*)d_in[0];
  const float* f_ln_w  = (const float*)d_in[1];
  const float* f_ln_b  = (const float*)d_in[2];
  const float* f_in_w  = (const float*)d_in[3];
  const float* f_cw    = (const float*)d_in[4];
  const float* f_cb    = (const float*)d_in[5];
  const float* f_dtb   = (const float*)d_in[6];
  const float* f_alog  = (const float*)d_in[7];
  const float* f_D     = (const float*)d_in[8];
  const float* f_nw    = (const float*)d_in[9];
  const float* f_ow    = (const float*)d_in[10];
  const float* b_ln_w  = (const float*)d_in[11];
  const float* b_ln_b  = (const float*)d_in[12];
  const float* b_in_w  = (const float*)d_in[13];
  const float* b_cw    = (const float*)d_in[14];
  const float* b_cb    = (const float*)d_in[15];
  const float* b_dtb   = (const float*)d_in[16];
  const float* b_alog  = (const float*)d_in[17];
  const float* b_D     = (const float*)d_in[18];
  const float* b_nw    = (const float*)d_in[19];
  const float* b_ow    = (const float*)d_in[20];
  float* out = (float*)d_out;

  char* ws = (char*)d_ws;
  size_t off = 0;
  auto carve = [&](size_t bytes) -> char* {
    off = (off + 255) & ~(size_t)255;
    char* p = ws + off;
    off += bytes;
    return p;
  };
  ushortT* XLN   = (ushortT*)carve((size_t)2 * ROWS * DM * 2);
  ushortT* WP1   = (ushortT*)carve((size_t)2 * NP1 * DM * 2);
  ushortT* W2    = (ushortT*)carve((size_t)2 * DM * DI * 2);
  ushortT* ZXB   = (ushortT*)carve((size_t)2 * ROWS * NP1 * 2);
  float*   DTT   = (float*)carve((size_t)2 * ROWS * 128 * 4);
  ushortT* YB    = (ushortT*)carve((size_t)2 * ROWS * DI * 2);
  ushortT* YN    = (ushortT*)carve((size_t)2 * ROWS * DI * 2);
  ushortT* MOUTB = (ushortT*)carve((size_t)2 * ROWS * DM * 2);
  ushortT* SLOCB = (ushortT*)carve((size_t)96 * NCHUNK * 4096 * 2);
  ushortT* SINIB = (ushortT*)carve((size_t)96 * (NCHUNK - 1) * 4096 * 2);
  ushortT* BCC   = (ushortT*)carve((size_t)4 * NCHUNK * 2 * 4096 * 2);
  float*   CWG   = (float*)carve((size_t)2 * ROWS * HH * 4);

  // LN both dirs per x-row (blocks 0..2047) + weight cvt (2048+)
  prep_kernel<<<4096, 256, 0, stream>>>(x, f_ln_w, f_ln_b, b_ln_w, b_ln_b, XLN,
                                        f_in_w, b_in_w, f_ow, b_ow, WP1, W2);

  // in_proj: [2048,768] x [3328,768]^T (256x256 tile, 8 waves)
  gemm256_kernel<<<dim3(NP1 / 256, ROWS / 256, 2), 512, 0, stream>>>(
      XLN, WP1, DTT, ZXB, DM, DM, DM, NP1,
      (long)ROWS * DM, (long)NP1 * DM, (long)ROWS * 128, (long)ROWS * NP1);

  // B/C conv once per (dirb, chunk), pre-swizzled
  convbc_kernel<<<dim3(NCHUNK, 4), 256, 0, stream>>>(ZXB, f_cw, f_cb, b_cw, b_cb, BCC);

  // fused X-conv + SSD pass 1 (+ D*x)
  ssd_chunk_kernel<<<dim3(96, NCHUNK), 256, 0, stream>>>(
      ZXB, BCC, DTT, f_cw, f_cb, b_cw, b_cb, f_dtb, f_alog, b_dtb, b_alog,
      f_D, b_D, YB, SLOCB, CWG);

  // pass 2 (prefix), pass 3 (MFMA fixup, RMW into YB)
  chunk_prefix_kernel<<<96, 256, 0, stream>>>(SLOCB, CWG, SINIB);
  fixup_kernel<<<dim3(96, NCHUNK - 1), 256, 0, stream>>>(BCC, SINIB, CWG, YB);

  // gate + rmsnorm
  gate_norm_kernel<<<4096, 192, 0, stream>>>(YB, ZXB, f_nw, b_nw, YN);

  // out_proj: [2048,1536] x [768,1536]^T -> bf16 MOUTB
  gemm_bf16<<<dim3(DM / 128, ROWS / 128, 2), 256, 0, stream>>>(
      YN, W2, MOUTB, DI, DI, DI, DM,
      (long)ROWS * DI, (long)DM * DI, (long)ROWS * DM);

  // combine
  combine_kernel<<<2048, 128, 0, stream>>>(x, MOUTB, MOUTB + (size_t)ROWS * DM, out);
}